// Round 13
// baseline (584.746 us; speedup 1.0000x reference)
//
#include <hip/hip_runtime.h>
#include <stdint.h>

// ---------------------------------------------------------------------------
// Swin block: LN1 -> shift+window -> QKV -> windowed MSA (+relpos bias, +shift
// mask) -> proj (+reverse/unshift, +residual) -> LN2 -> FC1+GELU -> FC2
// (+residual).  B=8, C=384, H=W=96, NH=12, WIN=8, SHIFT=4, HID=1536.
// Tokens M = 73728, windows per image nW = 144, B_ = 1152, N=64, HD=32.
//
// Structure: 128x128 tile, BK=64, dbuf LDS, XOR swizzle (0 conflicts), XCD
// swizzle, bf16 residual trunk (r12, 568us).  This round: K-loop in the
// verified single-barrier 2-phase form (T3 recipe / m248):
//   {STAGE(next); ds_read+MFMA(cur); vmcnt(0); barrier}   -- 1 barrier/step
// (was: {STAGE; vmcnt(8); barrier; COMPUTE; barrier} -- 2 barriers/step).
// Also: 4 weight-cvt dispatches merged into 1.
// ---------------------------------------------------------------------------

typedef __attribute__((ext_vector_type(8))) __bf16 bf16x8;
typedef __attribute__((ext_vector_type(4))) float f32x4;

#define MTOK 73728
#define QSZ  28311552u   /* 1152*12*64*32 elems per q/k/v matrix */

__device__ __forceinline__ unsigned short f2bf(float f) {
  __bf16 h = (__bf16)f;
  return __builtin_bit_cast(unsigned short, h);
}
__device__ __forceinline__ float bf2f(uint32_t u) {
  uint32_t x = (u & 0xffffu) << 16;
  return __builtin_bit_cast(float, x);
}
__device__ __forceinline__ uint32_t pack2(float a, float b) {
  return (uint32_t)f2bf(a) | ((uint32_t)f2bf(b) << 16);
}

__device__ __forceinline__ void async_cp16(const void* g, void* lds) {
  __builtin_amdgcn_global_load_lds(
      (void __attribute__((address_space(1)))*)(uintptr_t)g,
      (void __attribute__((address_space(3)))*)(uint32_t)(uintptr_t)lds,
      16, 0, 0);
}

__device__ __forceinline__ f32x4 mfma16(bf16x8 a, bf16x8 b, f32x4 c) {
  return __builtin_amdgcn_mfma_f32_16x16x32_bf16(a, b, c, 0, 0, 0);
}

// ---------------------------------------------------------------------------
// merged fp32 -> bf16 weight conversion (targets contiguous in workspace)
// ---------------------------------------------------------------------------
__global__ __launch_bounds__(256)
void cvt_all_kernel(const float* __restrict__ s0, const float* __restrict__ s1,
                    const float* __restrict__ s2, const float* __restrict__ s3,
                    unsigned short* __restrict__ out) {
  const int i = blockIdx.x * 256 + threadIdx.x;
  float v;
  if (i < 442368) v = s0[i];                       // qkv_w  1152*384
  else if (i < 589824) v = s1[i - 442368];         // proj_w  384*384
  else if (i < 1179648) v = s2[i - 589824];        // fc1_w  1536*384
  else v = s3[i - 1179648];                        // fc2_w  384*1536
  out[i] = f2bf(v);
}

// ---------------------------------------------------------------------------
// LN1 + roll(-4,-4) + window partition.  One wave per output token.
// ---------------------------------------------------------------------------
__global__ __launch_bounds__(256)
void ln1_kernel(const float* __restrict__ x, const float* __restrict__ w,
                const float* __restrict__ b, unsigned short* __restrict__ out) {
  const int t = blockIdx.x * 4 + (threadIdx.x >> 6);
  const int lane = threadIdx.x & 63;
  const int b_ = t >> 6, tok = t & 63;
  const int wI = b_ % 144, bb = b_ / 144;
  const int ph = ((wI / 12) * 8 + (tok >> 3) + 4) % 96;
  const int pw = ((wI % 12) * 8 + (tok & 7) + 4) % 96;
  const float* src = x + ((size_t)(bb * 96 + ph) * 96 + pw) * 384;
  float v[6];
  float s = 0.f, s2 = 0.f;
#pragma unroll
  for (int j = 0; j < 6; ++j) {
    v[j] = src[lane + j * 64];
    s += v[j];
    s2 += v[j] * v[j];
  }
#pragma unroll
  for (int m = 1; m < 64; m <<= 1) {
    s += __shfl_xor(s, m, 64);
    s2 += __shfl_xor(s2, m, 64);
  }
  const float mu = s * (1.f / 384.f);
  const float rs = rsqrtf(s2 * (1.f / 384.f) - mu * mu + 1e-5f);
#pragma unroll
  for (int j = 0; j < 6; ++j) {
    const int c = lane + j * 64;
    out[(size_t)t * 384 + c] = f2bf((v[j] - mu) * rs * w[c] + b[c]);
  }
}

// ---------------------------------------------------------------------------
// LN2 over xo (bf16, pixel-major), paired 4B loads/stores, writes bf16.
// ---------------------------------------------------------------------------
__global__ __launch_bounds__(256)
void ln2_kernel(const unsigned short* __restrict__ xo,
                const float* __restrict__ w, const float* __restrict__ b,
                unsigned short* __restrict__ out) {
  const int t = blockIdx.x * 4 + (threadIdx.x >> 6);
  const int lane = threadIdx.x & 63;
  const unsigned short* src = xo + (size_t)t * 384;
  float v[6];
  float s = 0.f, s2 = 0.f;
#pragma unroll
  for (int j = 0; j < 3; ++j) {
    const uint32_t u = *(const uint32_t*)&src[j * 128 + lane * 2];
    const float a = bf2f(u), c = bf2f(u >> 16);
    v[2 * j] = a;
    v[2 * j + 1] = c;
    s += a + c;
    s2 += a * a + c * c;
  }
#pragma unroll
  for (int m = 1; m < 64; m <<= 1) {
    s += __shfl_xor(s, m, 64);
    s2 += __shfl_xor(s2, m, 64);
  }
  const float mu = s * (1.f / 384.f);
  const float rs = rsqrtf(s2 * (1.f / 384.f) - mu * mu + 1e-5f);
#pragma unroll
  for (int j = 0; j < 3; ++j) {
    const int c0 = j * 128 + lane * 2;
    *(uint32_t*)&out[(size_t)t * 384 + c0] =
        pack2((v[2 * j] - mu) * rs * w[c0] + b[c0],
              (v[2 * j + 1] - mu) * rs * w[c0 + 1] + b[c0 + 1]);
  }
}

// ---------------------------------------------------------------------------
// bf16 GEMM: C[M,N] = A[M,K] @ B[N,K]^T (+bias), 128x128 tile, BK=64,
// 4 waves (2x2), 16x16x32 MFMA.  Single-barrier 2-phase K-loop (T3 recipe):
//   prologue: STAGE(0); vmcnt(0); barrier
//   iter t:   STAGE(next); ds_read+MFMA(cur); vmcnt(0); barrier
//   epilogue: ds_read+MFMA(last)
// Safety: buf(next)'s prior readers finished (their lgkmcnt(0) preceded the
// previous barrier); vmcnt(0)+barrier publishes the stage to all waves.
// XOR-swizzled LDS (conflict-free).  XCD-chunked block swizzle.
// EPI: 0=QKV scatter (q scaled), 1=proj+reverse+residual(fp32 x)->xo bf16,
//      2=GELU->h1 bf16, 3=+xo(bf16) residual->d_out fp32.
// ---------------------------------------------------------------------------
template <int EPI>
__global__ __launch_bounds__(256, 2)
void gemm_bt(const unsigned short* __restrict__ A,
             const unsigned short* __restrict__ Bw,
             const float* __restrict__ bias, const void* __restrict__ res,
             void* __restrict__ out0, int M, int N, int K) {
  __shared__ unsigned short As[2][128 * 64];
  __shared__ unsigned short Bs[2][128 * 64];
  const int tid = threadIdx.x;
  const int wave = tid >> 6, lane = tid & 63;
  const int lr = lane & 15, kg = lane >> 4;
  const int wm = wave >> 1, wn = wave & 1;

  // XCD-chunked bijective block swizzle (nwg % 8 == 0 for all our grids)
  const int gx = gridDim.x;
  const int nwg = gx * gridDim.y;
  int bid = blockIdx.y * gx + blockIdx.x;
  bid = (bid & 7) * (nwg >> 3) + (bid >> 3);
  const int tile_n = (bid % gx) * 128;
  const int tile_m = (bid / gx) * 128;

  // staging: lane covers row (lane>>3) of the 8-row stripe, 16B granule
  // (lane&7); source granule pre-swizzled so that a swizzled READ is correct.
  const int srow = lane >> 3;
  const int scol = ((lane & 7) ^ srow) * 8;   // bf16 elems

  const f32x4 z4 = {0.f, 0.f, 0.f, 0.f};
  f32x4 acc[4][4];
#pragma unroll
  for (int i = 0; i < 4; ++i)
#pragma unroll
    for (int j = 0; j < 4; ++j) acc[i][j] = z4;

  const unsigned short* Ab = A + (size_t)tile_m * K;
  const unsigned short* Bb = Bw + (size_t)tile_n * K;

  auto STAGE = [&](int buf, int kt) {   // 8 global_load_lds per thread
#pragma unroll
    for (int i = 0; i < 4; ++i) {
      const int r0 = wave * 32 + i * 8;
      async_cp16(&Ab[(size_t)(r0 + srow) * K + kt + scol], &As[buf][r0 * 64]);
      async_cp16(&Bb[(size_t)(r0 + srow) * K + kt + scol], &Bs[buf][r0 * 64]);
    }
  };

  auto COMPUTE = [&](int buf) {
#pragma unroll
    for (int kk = 0; kk < 2; ++kk) {
      const int gsw = ((kk * 4 + kg) ^ (lr & 7)) * 8;  // swizzled granule
      bf16x8 af[4], bfr[4];
#pragma unroll
      for (int mf = 0; mf < 4; ++mf)
        af[mf] = *(const bf16x8*)&As[buf][(wm * 64 + mf * 16 + lr) * 64 + gsw];
#pragma unroll
      for (int nf = 0; nf < 4; ++nf)
        bfr[nf] = *(const bf16x8*)&Bs[buf][(wn * 64 + nf * 16 + lr) * 64 + gsw];
#pragma unroll
      for (int mf = 0; mf < 4; ++mf)
#pragma unroll
        for (int nf = 0; nf < 4; ++nf)
          acc[mf][nf] = mfma16(af[mf], bfr[nf], acc[mf][nf]);
    }
  };

  // --- single-barrier 2-phase pipeline (verified recipe form) ---
  STAGE(0, 0);
  asm volatile("s_waitcnt vmcnt(0)" ::: "memory");
  __builtin_amdgcn_s_barrier();
  int cur = 0;
  for (int kt = 64; kt < K; kt += 64) {
    STAGE(cur ^ 1, kt);          // issue next-tile loads (hide under compute)
    COMPUTE(cur);                // ds_read + MFMA (compiler-waited lgkmcnt)
    asm volatile("s_waitcnt vmcnt(0)" ::: "memory");  // next tile landed
    __builtin_amdgcn_s_barrier();                     // publish to all waves
    cur ^= 1;
  }
  COMPUTE(cur);

#pragma unroll
  for (int mf = 0; mf < 4; ++mf) {
#pragma unroll
    for (int nf = 0; nf < 4; ++nf) {
#pragma unroll
      for (int r = 0; r < 4; ++r) {
        const int row = tile_m + wm * 64 + mf * 16 + kg * 4 + r;
        const int col = tile_n + wn * 64 + nf * 16 + lr;
        float v = acc[mf][nf][r] + bias[col];
        if constexpr (EPI == 0) {
          const int s = col / 384;
          const int cc = col - s * 384;
          const int hh = cc >> 5, d = cc & 31;
          if (s == 0) v *= 0.17677669529663689f;  // HD^-0.5
          const int b_ = row >> 6, tok = row & 63;
          ((unsigned short*)out0)[(size_t)s * QSZ +
                                  ((size_t)(b_ * 12 + hh) * 64 + tok) * 32 + d] =
              f2bf(v);
        } else if constexpr (EPI == 1) {
          const int b_ = row >> 6, tok = row & 63;
          const int wI = b_ % 144, bb = b_ / 144;
          const int ph = ((wI / 12) * 8 + (tok >> 3) + 4) % 96;
          const int pw = ((wI % 12) * 8 + (tok & 7) + 4) % 96;
          const size_t pix = (size_t)(bb * 96 + ph) * 96 + pw;
          // res = original x (fp32, raw-reshape layout); out = xo bf16
          ((unsigned short*)out0)[pix * 384 + col] =
              f2bf(((const float*)res)[pix * 384 + col] + v);
        } else if constexpr (EPI == 2) {
          // cheap GELU: v * sigmoid(1.702 v)
          const float g = v / (1.f + __expf(-1.702f * v));
          ((unsigned short*)out0)[(size_t)row * 1536 + col] = f2bf(g);
        } else {
          // res = xo bf16; out = d_out fp32
          const float rv =
              bf2f(((const unsigned short*)res)[(size_t)row * 384 + col]);
          ((float*)out0)[(size_t)row * 384 + col] = rv + v;
        }
      }
    }
  }
}

// ---------------------------------------------------------------------------
// Windowed attention: one block (4 waves) per (b_, head).
// q,k,v: (B_, NH, 64, 32) bf16.  out_t: (B_*64, 384) bf16 token-major.
// P and vT LDS tiles XOR-swizzled (scalar writes swizzled, b128 reads too).
// ---------------------------------------------------------------------------
__global__ __launch_bounds__(256)
void attn_kernel(const unsigned short* __restrict__ qkv,
                 const float* __restrict__ rpb,
                 unsigned short* __restrict__ out_t) {
  const int bh = blockIdx.x;
  const int b_ = bh / 12, h = bh % 12;
  const int tid = threadIdx.x, wave = tid >> 6, lane = tid & 63;
  const int lr = lane & 15, kg = lane >> 4;
  const unsigned short* qb = qkv + (size_t)(b_ * 12 + h) * 64 * 32;
  const unsigned short* kb = qb + QSZ;
  const unsigned short* vb = qb + 2u * QSZ;

  __shared__ unsigned short P[64 * 64];
  __shared__ unsigned short vT[32 * 64];

  // stage v^T into LDS: vT[d][tok], col swizzled by (d&7)<<3
  {
    const int tok = tid >> 2, d0 = (tid & 3) * 8;
    const unsigned short* vp = &vb[tok * 32 + d0];
#pragma unroll
    for (int j = 0; j < 8; ++j)
      vT[(d0 + j) * 64 + (tok ^ (j << 3))] = vp[j];
  }

  // QK^T: rows wave*16..+15, all 64 cols
  const bf16x8 aq = *(const bf16x8*)&qb[(wave * 16 + lr) * 32 + kg * 8];
  f32x4 sc[4];
  const f32x4 z4 = {0.f, 0.f, 0.f, 0.f};
#pragma unroll
  for (int cb = 0; cb < 4; ++cb) {
    const bf16x8 bk = *(const bf16x8*)&kb[(cb * 16 + lr) * 32 + kg * 8];
    sc[cb] = mfma16(aq, bk, z4);
  }

  // bias + mask + softmax (row fully inside one 16-lane group)
  const int wI = b_ % 144;
  const int whi = wI / 12, wwi = wI % 12;
#pragma unroll
  for (int r = 0; r < 4; ++r) {
    const int row = wave * 16 + kg * 4 + r;
    const int rh = (whi < 11) ? 0 : (((row >> 3) < 4) ? 1 : 2);
    const int rw = (wwi < 11) ? 0 : (((row & 7) < 4) ? 1 : 2);
    float sv[4];
    float mx = -1e30f;
#pragma unroll
    for (int cb = 0; cb < 4; ++cb) {
      const int col = cb * 16 + lr;
      const int dr = (row >> 3) - (col >> 3) + 7;
      const int dc = (row & 7) - (col & 7) + 7;
      const float bias = rpb[(dr * 15 + dc) * 12 + h];
      const int ch = (whi < 11) ? 0 : (((col >> 3) < 4) ? 1 : 2);
      const int cw = (wwi < 11) ? 0 : (((col & 7) < 4) ? 1 : 2);
      float val = sc[cb][r] + bias + ((rh == ch && rw == cw) ? 0.f : -100.f);
      sv[cb] = val;
      mx = fmaxf(mx, val);
    }
#pragma unroll
    for (int o = 1; o < 16; o <<= 1) mx = fmaxf(mx, __shfl_xor(mx, o, 64));
    float sum = 0.f;
#pragma unroll
    for (int cb = 0; cb < 4; ++cb) {
      sv[cb] = __expf(sv[cb] - mx);
      sum += sv[cb];
    }
#pragma unroll
    for (int o = 1; o < 16; o <<= 1) sum += __shfl_xor(sum, o, 64);
    const float inv = 1.f / sum;
    const int psw = (row & 7) << 3;
#pragma unroll
    for (int cb = 0; cb < 4; ++cb)
      P[row * 64 + ((cb * 16 + lr) ^ psw)] = f2bf(sv[cb] * inv);
  }
  __syncthreads();

  // PV: out rows wave*16..+15, cols 0..31; K=64 in two 32-slices
  f32x4 o0 = z4, o1 = z4;
  const int rsw = (lr & 7) << 3;
#pragma unroll
  for (int ks = 0; ks < 2; ++ks) {
    const int e = (ks * 32 + kg * 8);
    const bf16x8 ap =
        *(const bf16x8*)&P[(wave * 16 + lr) * 64 + (e ^ rsw)];
    const bf16x8 b0 = *(const bf16x8*)&vT[(0 + lr) * 64 + (e ^ rsw)];
    const bf16x8 b1 = *(const bf16x8*)&vT[(16 + lr) * 64 + (e ^ rsw)];
    o0 = mfma16(ap, b0, o0);
    o1 = mfma16(ap, b1, o1);
  }
  unsigned short* ob = out_t + (size_t)(b_ * 64) * 384 + h * 32;
#pragma unroll
  for (int r = 0; r < 4; ++r) {
    const int tok = wave * 16 + kg * 4 + r;
    ob[(size_t)tok * 384 + lr] = f2bf(o0[r]);
    ob[(size_t)tok * 384 + 16 + lr] = f2bf(o1[r]);
  }
}

// ---------------------------------------------------------------------------
extern "C" void kernel_launch(void* const* d_in, const int* in_sizes, int n_in,
                              void* d_out, int out_size, void* d_ws,
                              size_t ws_size, hipStream_t stream) {
  const float* x      = (const float*)d_in[0];
  const float* qkv_w  = (const float*)d_in[1];
  const float* qkv_b  = (const float*)d_in[2];
  const float* rpb    = (const float*)d_in[3];
  const float* proj_w = (const float*)d_in[4];
  const float* proj_b = (const float*)d_in[5];
  const float* n1w    = (const float*)d_in[6];
  const float* n1b    = (const float*)d_in[7];
  const float* n2w    = (const float*)d_in[8];
  const float* n2b    = (const float*)d_in[9];
  const float* fc1_w  = (const float*)d_in[10];
  const float* fc1_b  = (const float*)d_in[11];
  const float* fc2_w  = (const float*)d_in[12];
  const float* fc2_b  = (const float*)d_in[13];

  char* ws = (char*)d_ws;
  const size_t SZ_A = 56623104;    // 73728*384*2  (bf16 act)
  const size_t SZ_Q = 3 * SZ_A;    // q,k,v bf16

  unsigned short* Xw    = (unsigned short*)(ws);
  unsigned short* qkv   = (unsigned short*)(ws + SZ_A);
  unsigned short* xo    = (unsigned short*)(ws + SZ_A + SZ_Q);        // bf16
  unsigned short* xon   = (unsigned short*)(ws + SZ_A + SZ_Q + SZ_A); // bf16
  unsigned short* wbuf  = (unsigned short*)(ws + SZ_A + SZ_Q + 2 * SZ_A);
  unsigned short* wqkv  = wbuf;
  unsigned short* wproj = wqkv + 1152 * 384;
  unsigned short* wfc1  = wproj + 384 * 384;
  unsigned short* wfc2  = wfc1 + 1536 * 384;
  unsigned short* attn_o = Xw;               // reuse after QKV consumed Xw
  unsigned short* h1     = (unsigned short*)ws;  // 226.5MB, reuses Xw+qkv

  cvt_all_kernel<<<6912, 256, 0, stream>>>(qkv_w, proj_w, fc1_w, fc2_w, wbuf);

  ln1_kernel<<<MTOK / 4, 256, 0, stream>>>(x, n1w, n1b, Xw);

  gemm_bt<0><<<dim3(9, 576), 256, 0, stream>>>(Xw, wqkv, qkv_b, nullptr,
                                               qkv, MTOK, 1152, 384);

  attn_kernel<<<13824, 256, 0, stream>>>(qkv, rpb, attn_o);

  gemm_bt<1><<<dim3(3, 576), 256, 0, stream>>>(attn_o, wproj, proj_b, x,
                                               xo, MTOK, 384, 384);

  ln2_kernel<<<MTOK / 4, 256, 0, stream>>>(xo, n2w, n2b, xon);

  gemm_bt<2><<<dim3(12, 576), 256, 0, stream>>>(xon, wfc1, fc1_b, nullptr,
                                                h1, MTOK, 1536, 384);

  gemm_bt<3><<<dim3(3, 576), 256, 0, stream>>>(h1, wfc2, fc2_b, xo,
                                               (float*)d_out, MTOK, 384, 1536);
}

// Round 14
// 566.000 us; speedup vs baseline: 1.0331x; 1.0331x over previous
//
#include <hip/hip_runtime.h>
#include <stdint.h>

// ---------------------------------------------------------------------------
// Swin block: LN1 -> shift+window -> QKV -> windowed MSA (+relpos bias, +shift
// mask) -> proj (+reverse/unshift, +residual) -> LN2 -> FC1+GELU -> FC2
// (+residual).  B=8, C=384, H=W=96, NH=12, WIN=8, SHIFT=4, HID=1536.
// Tokens M = 73728, windows per image nW = 144, B_ = 1152, N=64, HD=32.
//
// Measured-best configuration (r12 = 568.6 us) restored after r13 A/B showed
// the single-barrier K-loop regresses (-16 us): two-barrier counted-vmcnt(8)
// schedule, 128x128 tile, BK=64, dbuf LDS, XOR swizzle (0 conflicts), XCD
// swizzle, bf16 residual trunk, merged weight-cvt dispatch.
// ---------------------------------------------------------------------------

typedef __attribute__((ext_vector_type(8))) __bf16 bf16x8;
typedef __attribute__((ext_vector_type(4))) float f32x4;

#define MTOK 73728
#define QSZ  28311552u   /* 1152*12*64*32 elems per q/k/v matrix */

__device__ __forceinline__ unsigned short f2bf(float f) {
  __bf16 h = (__bf16)f;
  return __builtin_bit_cast(unsigned short, h);
}
__device__ __forceinline__ float bf2f(uint32_t u) {
  uint32_t x = (u & 0xffffu) << 16;
  return __builtin_bit_cast(float, x);
}
__device__ __forceinline__ uint32_t pack2(float a, float b) {
  return (uint32_t)f2bf(a) | ((uint32_t)f2bf(b) << 16);
}

__device__ __forceinline__ void async_cp16(const void* g, void* lds) {
  __builtin_amdgcn_global_load_lds(
      (void __attribute__((address_space(1)))*)(uintptr_t)g,
      (void __attribute__((address_space(3)))*)(uint32_t)(uintptr_t)lds,
      16, 0, 0);
}

__device__ __forceinline__ f32x4 mfma16(bf16x8 a, bf16x8 b, f32x4 c) {
  return __builtin_amdgcn_mfma_f32_16x16x32_bf16(a, b, c, 0, 0, 0);
}

// ---------------------------------------------------------------------------
// merged fp32 -> bf16 weight conversion (targets contiguous in workspace)
// ---------------------------------------------------------------------------
__global__ __launch_bounds__(256)
void cvt_all_kernel(const float* __restrict__ s0, const float* __restrict__ s1,
                    const float* __restrict__ s2, const float* __restrict__ s3,
                    unsigned short* __restrict__ out) {
  const int i = blockIdx.x * 256 + threadIdx.x;
  float v;
  if (i < 442368) v = s0[i];                       // qkv_w  1152*384
  else if (i < 589824) v = s1[i - 442368];         // proj_w  384*384
  else if (i < 1179648) v = s2[i - 589824];        // fc1_w  1536*384
  else v = s3[i - 1179648];                        // fc2_w  384*1536
  out[i] = f2bf(v);
}

// ---------------------------------------------------------------------------
// LN1 + roll(-4,-4) + window partition.  One wave per output token.
// ---------------------------------------------------------------------------
__global__ __launch_bounds__(256)
void ln1_kernel(const float* __restrict__ x, const float* __restrict__ w,
                const float* __restrict__ b, unsigned short* __restrict__ out) {
  const int t = blockIdx.x * 4 + (threadIdx.x >> 6);
  const int lane = threadIdx.x & 63;
  const int b_ = t >> 6, tok = t & 63;
  const int wI = b_ % 144, bb = b_ / 144;
  const int ph = ((wI / 12) * 8 + (tok >> 3) + 4) % 96;
  const int pw = ((wI % 12) * 8 + (tok & 7) + 4) % 96;
  const float* src = x + ((size_t)(bb * 96 + ph) * 96 + pw) * 384;
  float v[6];
  float s = 0.f, s2 = 0.f;
#pragma unroll
  for (int j = 0; j < 6; ++j) {
    v[j] = src[lane + j * 64];
    s += v[j];
    s2 += v[j] * v[j];
  }
#pragma unroll
  for (int m = 1; m < 64; m <<= 1) {
    s += __shfl_xor(s, m, 64);
    s2 += __shfl_xor(s2, m, 64);
  }
  const float mu = s * (1.f / 384.f);
  const float rs = rsqrtf(s2 * (1.f / 384.f) - mu * mu + 1e-5f);
#pragma unroll
  for (int j = 0; j < 6; ++j) {
    const int c = lane + j * 64;
    out[(size_t)t * 384 + c] = f2bf((v[j] - mu) * rs * w[c] + b[c]);
  }
}

// ---------------------------------------------------------------------------
// LN2 over xo (bf16, pixel-major), paired 4B loads/stores, writes bf16.
// ---------------------------------------------------------------------------
__global__ __launch_bounds__(256)
void ln2_kernel(const unsigned short* __restrict__ xo,
                const float* __restrict__ w, const float* __restrict__ b,
                unsigned short* __restrict__ out) {
  const int t = blockIdx.x * 4 + (threadIdx.x >> 6);
  const int lane = threadIdx.x & 63;
  const unsigned short* src = xo + (size_t)t * 384;
  float v[6];
  float s = 0.f, s2 = 0.f;
#pragma unroll
  for (int j = 0; j < 3; ++j) {
    const uint32_t u = *(const uint32_t*)&src[j * 128 + lane * 2];
    const float a = bf2f(u), c = bf2f(u >> 16);
    v[2 * j] = a;
    v[2 * j + 1] = c;
    s += a + c;
    s2 += a * a + c * c;
  }
#pragma unroll
  for (int m = 1; m < 64; m <<= 1) {
    s += __shfl_xor(s, m, 64);
    s2 += __shfl_xor(s2, m, 64);
  }
  const float mu = s * (1.f / 384.f);
  const float rs = rsqrtf(s2 * (1.f / 384.f) - mu * mu + 1e-5f);
#pragma unroll
  for (int j = 0; j < 3; ++j) {
    const int c0 = j * 128 + lane * 2;
    *(uint32_t*)&out[(size_t)t * 384 + c0] =
        pack2((v[2 * j] - mu) * rs * w[c0] + b[c0],
              (v[2 * j + 1] - mu) * rs * w[c0 + 1] + b[c0 + 1]);
  }
}

// ---------------------------------------------------------------------------
// bf16 GEMM: C[M,N] = A[M,K] @ B[N,K]^T (+bias), 128x128 tile, BK=64,
// 4 waves (2x2), 16x16x32 MFMA.  Double-buffered LDS with COUNTED vmcnt
// pipeline (measured best): per K-step {STAGE(next); vmcnt(8); barrier;
// COMPUTE(cur); barrier} -- the 8 loads issued this step stay in flight
// across the whole compute phase; only the previous step's 8 are waited.
// XOR-swizzled LDS (0 conflicts).  XCD-chunked block swizzle.
// EPI: 0=QKV scatter (q scaled), 1=proj+reverse+residual(fp32 x)->xo bf16,
//      2=GELU->h1 bf16, 3=+xo(bf16) residual->d_out fp32.
// ---------------------------------------------------------------------------
template <int EPI>
__global__ __launch_bounds__(256, 2)
void gemm_bt(const unsigned short* __restrict__ A,
             const unsigned short* __restrict__ Bw,
             const float* __restrict__ bias, const void* __restrict__ res,
             void* __restrict__ out0, int M, int N, int K) {
  __shared__ unsigned short As[2][128 * 64];
  __shared__ unsigned short Bs[2][128 * 64];
  const int tid = threadIdx.x;
  const int wave = tid >> 6, lane = tid & 63;
  const int lr = lane & 15, kg = lane >> 4;
  const int wm = wave >> 1, wn = wave & 1;

  // XCD-chunked bijective block swizzle (nwg % 8 == 0 for all our grids)
  const int gx = gridDim.x;
  const int nwg = gx * gridDim.y;
  int bid = blockIdx.y * gx + blockIdx.x;
  bid = (bid & 7) * (nwg >> 3) + (bid >> 3);
  const int tile_n = (bid % gx) * 128;
  const int tile_m = (bid / gx) * 128;

  // staging: lane covers row (lane>>3) of the 8-row stripe, 16B granule
  // (lane&7); source granule pre-swizzled so that a swizzled READ is correct.
  const int srow = lane >> 3;
  const int scol = ((lane & 7) ^ srow) * 8;   // bf16 elems

  const f32x4 z4 = {0.f, 0.f, 0.f, 0.f};
  f32x4 acc[4][4];
#pragma unroll
  for (int i = 0; i < 4; ++i)
#pragma unroll
    for (int j = 0; j < 4; ++j) acc[i][j] = z4;

  const unsigned short* Ab = A + (size_t)tile_m * K;
  const unsigned short* Bb = Bw + (size_t)tile_n * K;

  auto STAGE = [&](int buf, int kt) {   // 8 global_load_lds per thread
#pragma unroll
    for (int i = 0; i < 4; ++i) {
      const int r0 = wave * 32 + i * 8;
      async_cp16(&Ab[(size_t)(r0 + srow) * K + kt + scol], &As[buf][r0 * 64]);
      async_cp16(&Bb[(size_t)(r0 + srow) * K + kt + scol], &Bs[buf][r0 * 64]);
    }
  };

  auto COMPUTE = [&](int buf) {
#pragma unroll
    for (int kk = 0; kk < 2; ++kk) {
      const int gsw = ((kk * 4 + kg) ^ (lr & 7)) * 8;  // swizzled granule
      bf16x8 af[4], bfr[4];
#pragma unroll
      for (int mf = 0; mf < 4; ++mf)
        af[mf] = *(const bf16x8*)&As[buf][(wm * 64 + mf * 16 + lr) * 64 + gsw];
#pragma unroll
      for (int nf = 0; nf < 4; ++nf)
        bfr[nf] = *(const bf16x8*)&Bs[buf][(wn * 64 + nf * 16 + lr) * 64 + gsw];
#pragma unroll
      for (int mf = 0; mf < 4; ++mf)
#pragma unroll
        for (int nf = 0; nf < 4; ++nf)
          acc[mf][nf] = mfma16(af[mf], bfr[nf], acc[mf][nf]);
    }
  };

  STAGE(0, 0);                    // 8 outstanding
  int cur = 0;
  for (int kt = 64; kt < K; kt += 64) {
    STAGE(cur ^ 1, kt);           // +8 -> 16 outstanding
    asm volatile("s_waitcnt vmcnt(8)" ::: "memory");  // oldest 8 (cur) landed
    __builtin_amdgcn_s_barrier();                     // all waves' cur landed
    COMPUTE(cur);
    __builtin_amdgcn_s_barrier();  // all waves done reading cur
    cur ^= 1;
  }
  asm volatile("s_waitcnt vmcnt(0)" ::: "memory");
  __builtin_amdgcn_s_barrier();
  COMPUTE(cur);

#pragma unroll
  for (int mf = 0; mf < 4; ++mf) {
#pragma unroll
    for (int nf = 0; nf < 4; ++nf) {
#pragma unroll
      for (int r = 0; r < 4; ++r) {
        const int row = tile_m + wm * 64 + mf * 16 + kg * 4 + r;
        const int col = tile_n + wn * 64 + nf * 16 + lr;
        float v = acc[mf][nf][r] + bias[col];
        if constexpr (EPI == 0) {
          const int s = col / 384;
          const int cc = col - s * 384;
          const int hh = cc >> 5, d = cc & 31;
          if (s == 0) v *= 0.17677669529663689f;  // HD^-0.5
          const int b_ = row >> 6, tok = row & 63;
          ((unsigned short*)out0)[(size_t)s * QSZ +
                                  ((size_t)(b_ * 12 + hh) * 64 + tok) * 32 + d] =
              f2bf(v);
        } else if constexpr (EPI == 1) {
          const int b_ = row >> 6, tok = row & 63;
          const int wI = b_ % 144, bb = b_ / 144;
          const int ph = ((wI / 12) * 8 + (tok >> 3) + 4) % 96;
          const int pw = ((wI % 12) * 8 + (tok & 7) + 4) % 96;
          const size_t pix = (size_t)(bb * 96 + ph) * 96 + pw;
          // res = original x (fp32, raw-reshape layout); out = xo bf16
          ((unsigned short*)out0)[pix * 384 + col] =
              f2bf(((const float*)res)[pix * 384 + col] + v);
        } else if constexpr (EPI == 2) {
          // cheap GELU: v * sigmoid(1.702 v)
          const float g = v / (1.f + __expf(-1.702f * v));
          ((unsigned short*)out0)[(size_t)row * 1536 + col] = f2bf(g);
        } else {
          // res = xo bf16; out = d_out fp32
          const float rv =
              bf2f(((const unsigned short*)res)[(size_t)row * 384 + col]);
          ((float*)out0)[(size_t)row * 384 + col] = rv + v;
        }
      }
    }
  }
}

// ---------------------------------------------------------------------------
// Windowed attention: one block (4 waves) per (b_, head).
// q,k,v: (B_, NH, 64, 32) bf16.  out_t: (B_*64, 384) bf16 token-major.
// P and vT LDS tiles XOR-swizzled (scalar writes swizzled, b128 reads too).
// ---------------------------------------------------------------------------
__global__ __launch_bounds__(256)
void attn_kernel(const unsigned short* __restrict__ qkv,
                 const float* __restrict__ rpb,
                 unsigned short* __restrict__ out_t) {
  const int bh = blockIdx.x;
  const int b_ = bh / 12, h = bh % 12;
  const int tid = threadIdx.x, wave = tid >> 6, lane = tid & 63;
  const int lr = lane & 15, kg = lane >> 4;
  const unsigned short* qb = qkv + (size_t)(b_ * 12 + h) * 64 * 32;
  const unsigned short* kb = qb + QSZ;
  const unsigned short* vb = qb + 2u * QSZ;

  __shared__ unsigned short P[64 * 64];
  __shared__ unsigned short vT[32 * 64];

  // stage v^T into LDS: vT[d][tok], col swizzled by (d&7)<<3
  {
    const int tok = tid >> 2, d0 = (tid & 3) * 8;
    const unsigned short* vp = &vb[tok * 32 + d0];
#pragma unroll
    for (int j = 0; j < 8; ++j)
      vT[(d0 + j) * 64 + (tok ^ (j << 3))] = vp[j];
  }

  // QK^T: rows wave*16..+15, all 64 cols
  const bf16x8 aq = *(const bf16x8*)&qb[(wave * 16 + lr) * 32 + kg * 8];
  f32x4 sc[4];
  const f32x4 z4 = {0.f, 0.f, 0.f, 0.f};
#pragma unroll
  for (int cb = 0; cb < 4; ++cb) {
    const bf16x8 bk = *(const bf16x8*)&kb[(cb * 16 + lr) * 32 + kg * 8];
    sc[cb] = mfma16(aq, bk, z4);
  }

  // bias + mask + softmax (row fully inside one 16-lane group)
  const int wI = b_ % 144;
  const int whi = wI / 12, wwi = wI % 12;
#pragma unroll
  for (int r = 0; r < 4; ++r) {
    const int row = wave * 16 + kg * 4 + r;
    const int rh = (whi < 11) ? 0 : (((row >> 3) < 4) ? 1 : 2);
    const int rw = (wwi < 11) ? 0 : (((row & 7) < 4) ? 1 : 2);
    float sv[4];
    float mx = -1e30f;
#pragma unroll
    for (int cb = 0; cb < 4; ++cb) {
      const int col = cb * 16 + lr;
      const int dr = (row >> 3) - (col >> 3) + 7;
      const int dc = (row & 7) - (col & 7) + 7;
      const float bias = rpb[(dr * 15 + dc) * 12 + h];
      const int ch = (whi < 11) ? 0 : (((col >> 3) < 4) ? 1 : 2);
      const int cw = (wwi < 11) ? 0 : (((col & 7) < 4) ? 1 : 2);
      float val = sc[cb][r] + bias + ((rh == ch && rw == cw) ? 0.f : -100.f);
      sv[cb] = val;
      mx = fmaxf(mx, val);
    }
#pragma unroll
    for (int o = 1; o < 16; o <<= 1) mx = fmaxf(mx, __shfl_xor(mx, o, 64));
    float sum = 0.f;
#pragma unroll
    for (int cb = 0; cb < 4; ++cb) {
      sv[cb] = __expf(sv[cb] - mx);
      sum += sv[cb];
    }
#pragma unroll
    for (int o = 1; o < 16; o <<= 1) sum += __shfl_xor(sum, o, 64);
    const float inv = 1.f / sum;
    const int psw = (row & 7) << 3;
#pragma unroll
    for (int cb = 0; cb < 4; ++cb)
      P[row * 64 + ((cb * 16 + lr) ^ psw)] = f2bf(sv[cb] * inv);
  }
  __syncthreads();

  // PV: out rows wave*16..+15, cols 0..31; K=64 in two 32-slices
  f32x4 o0 = z4, o1 = z4;
  const int rsw = (lr & 7) << 3;
#pragma unroll
  for (int ks = 0; ks < 2; ++ks) {
    const int e = (ks * 32 + kg * 8);
    const bf16x8 ap =
        *(const bf16x8*)&P[(wave * 16 + lr) * 64 + (e ^ rsw)];
    const bf16x8 b0 = *(const bf16x8*)&vT[(0 + lr) * 64 + (e ^ rsw)];
    const bf16x8 b1 = *(const bf16x8*)&vT[(16 + lr) * 64 + (e ^ rsw)];
    o0 = mfma16(ap, b0, o0);
    o1 = mfma16(ap, b1, o1);
  }
  unsigned short* ob = out_t + (size_t)(b_ * 64) * 384 + h * 32;
#pragma unroll
  for (int r = 0; r < 4; ++r) {
    const int tok = wave * 16 + kg * 4 + r;
    ob[(size_t)tok * 384 + lr] = f2bf(o0[r]);
    ob[(size_t)tok * 384 + 16 + lr] = f2bf(o1[r]);
  }
}

// ---------------------------------------------------------------------------
extern "C" void kernel_launch(void* const* d_in, const int* in_sizes, int n_in,
                              void* d_out, int out_size, void* d_ws,
                              size_t ws_size, hipStream_t stream) {
  const float* x      = (const float*)d_in[0];
  const float* qkv_w  = (const float*)d_in[1];
  const float* qkv_b  = (const float*)d_in[2];
  const float* rpb    = (const float*)d_in[3];
  const float* proj_w = (const float*)d_in[4];
  const float* proj_b = (const float*)d_in[5];
  const float* n1w    = (const float*)d_in[6];
  const float* n1b    = (const float*)d_in[7];
  const float* n2w    = (const float*)d_in[8];
  const float* n2b    = (const float*)d_in[9];
  const float* fc1_w  = (const float*)d_in[10];
  const float* fc1_b  = (const float*)d_in[11];
  const float* fc2_w  = (const float*)d_in[12];
  const float* fc2_b  = (const float*)d_in[13];

  char* ws = (char*)d_ws;
  const size_t SZ_A = 56623104;    // 73728*384*2  (bf16 act)
  const size_t SZ_Q = 3 * SZ_A;    // q,k,v bf16

  unsigned short* Xw    = (unsigned short*)(ws);
  unsigned short* qkv   = (unsigned short*)(ws + SZ_A);
  unsigned short* xo    = (unsigned short*)(ws + SZ_A + SZ_Q);        // bf16
  unsigned short* xon   = (unsigned short*)(ws + SZ_A + SZ_Q + SZ_A); // bf16
  unsigned short* wbuf  = (unsigned short*)(ws + SZ_A + SZ_Q + 2 * SZ_A);
  unsigned short* wqkv  = wbuf;
  unsigned short* wproj = wqkv + 1152 * 384;
  unsigned short* wfc1  = wproj + 384 * 384;
  unsigned short* wfc2  = wfc1 + 1536 * 384;
  unsigned short* attn_o = Xw;               // reuse after QKV consumed Xw
  unsigned short* h1     = (unsigned short*)ws;  // 226.5MB, reuses Xw+qkv

  cvt_all_kernel<<<6912, 256, 0, stream>>>(qkv_w, proj_w, fc1_w, fc2_w, wbuf);

  ln1_kernel<<<MTOK / 4, 256, 0, stream>>>(x, n1w, n1b, Xw);

  gemm_bt<0><<<dim3(9, 576), 256, 0, stream>>>(Xw, wqkv, qkv_b, nullptr,
                                               qkv, MTOK, 1152, 384);

  attn_kernel<<<13824, 256, 0, stream>>>(qkv, rpb, attn_o);

  gemm_bt<1><<<dim3(3, 576), 256, 0, stream>>>(attn_o, wproj, proj_b, x,
                                               xo, MTOK, 384, 384);

  ln2_kernel<<<MTOK / 4, 256, 0, stream>>>(xo, n2w, n2b, xon);

  gemm_bt<2><<<dim3(12, 576), 256, 0, stream>>>(xon, wfc1, fc1_b, nullptr,
                                                h1, MTOK, 1536, 384);

  gemm_bt<3><<<dim3(3, 576), 256, 0, stream>>>(h1, wfc2, fc2_b, xo,
                                               (float*)d_out, MTOK, 384, 1536);
}

// Round 15
// 539.074 us; speedup vs baseline: 1.0847x; 1.0499x over previous
//
#include <hip/hip_runtime.h>
#include <stdint.h>

// ---------------------------------------------------------------------------
// Swin block: LN1 -> shift+window -> QKV -> windowed MSA (+relpos bias, +shift
// mask) -> proj (+reverse/unshift, +residual) -> LN2 -> FC1+GELU -> FC2
// (+residual).  B=8, C=384, H=W=96, NH=12, WIN=8, SHIFT=4, HID=1536.
// Tokens M = 73728, windows per image nW = 144, B_ = 1152, N=64, HD=32.
//
// r15: SINGLE-buffered LDS (32 KB) + XOR swizzle + 5 blocks/CU (m97-style).
// r14 model: with dbuf (64KB -> 2 blocks/CU) both blocks are barrier-locked
// in the same phase, so LDS-read (~768 cyc) and MFMA (~621 cyc) demands ADD
// per step-slot.  Single buffer frees LDS -> 5 staggered blocks/CU -> pipes
// overlap across blocks (m97/m114: implicit cross-block overlap beats
// explicit dbuf).  Everything else = r14 measured best (568/566 us).
// ---------------------------------------------------------------------------

typedef __attribute__((ext_vector_type(8))) __bf16 bf16x8;
typedef __attribute__((ext_vector_type(4))) float f32x4;

#define MTOK 73728
#define QSZ  28311552u   /* 1152*12*64*32 elems per q/k/v matrix */

__device__ __forceinline__ unsigned short f2bf(float f) {
  __bf16 h = (__bf16)f;
  return __builtin_bit_cast(unsigned short, h);
}
__device__ __forceinline__ float bf2f(uint32_t u) {
  uint32_t x = (u & 0xffffu) << 16;
  return __builtin_bit_cast(float, x);
}
__device__ __forceinline__ uint32_t pack2(float a, float b) {
  return (uint32_t)f2bf(a) | ((uint32_t)f2bf(b) << 16);
}

__device__ __forceinline__ void async_cp16(const void* g, void* lds) {
  __builtin_amdgcn_global_load_lds(
      (void __attribute__((address_space(1)))*)(uintptr_t)g,
      (void __attribute__((address_space(3)))*)(uint32_t)(uintptr_t)lds,
      16, 0, 0);
}

__device__ __forceinline__ f32x4 mfma16(bf16x8 a, bf16x8 b, f32x4 c) {
  return __builtin_amdgcn_mfma_f32_16x16x32_bf16(a, b, c, 0, 0, 0);
}

// ---------------------------------------------------------------------------
// merged fp32 -> bf16 weight conversion (targets contiguous in workspace)
// ---------------------------------------------------------------------------
__global__ __launch_bounds__(256)
void cvt_all_kernel(const float* __restrict__ s0, const float* __restrict__ s1,
                    const float* __restrict__ s2, const float* __restrict__ s3,
                    unsigned short* __restrict__ out) {
  const int i = blockIdx.x * 256 + threadIdx.x;
  float v;
  if (i < 442368) v = s0[i];                       // qkv_w  1152*384
  else if (i < 589824) v = s1[i - 442368];         // proj_w  384*384
  else if (i < 1179648) v = s2[i - 589824];        // fc1_w  1536*384
  else v = s3[i - 1179648];                        // fc2_w  384*1536
  out[i] = f2bf(v);
}

// ---------------------------------------------------------------------------
// LN1 + roll(-4,-4) + window partition.  One wave per output token.
// ---------------------------------------------------------------------------
__global__ __launch_bounds__(256)
void ln1_kernel(const float* __restrict__ x, const float* __restrict__ w,
                const float* __restrict__ b, unsigned short* __restrict__ out) {
  const int t = blockIdx.x * 4 + (threadIdx.x >> 6);
  const int lane = threadIdx.x & 63;
  const int b_ = t >> 6, tok = t & 63;
  const int wI = b_ % 144, bb = b_ / 144;
  const int ph = ((wI / 12) * 8 + (tok >> 3) + 4) % 96;
  const int pw = ((wI % 12) * 8 + (tok & 7) + 4) % 96;
  const float* src = x + ((size_t)(bb * 96 + ph) * 96 + pw) * 384;
  float v[6];
  float s = 0.f, s2 = 0.f;
#pragma unroll
  for (int j = 0; j < 6; ++j) {
    v[j] = src[lane + j * 64];
    s += v[j];
    s2 += v[j] * v[j];
  }
#pragma unroll
  for (int m = 1; m < 64; m <<= 1) {
    s += __shfl_xor(s, m, 64);
    s2 += __shfl_xor(s2, m, 64);
  }
  const float mu = s * (1.f / 384.f);
  const float rs = rsqrtf(s2 * (1.f / 384.f) - mu * mu + 1e-5f);
#pragma unroll
  for (int j = 0; j < 6; ++j) {
    const int c = lane + j * 64;
    out[(size_t)t * 384 + c] = f2bf((v[j] - mu) * rs * w[c] + b[c]);
  }
}

// ---------------------------------------------------------------------------
// LN2 over xo (bf16, pixel-major), paired 4B loads/stores, writes bf16.
// ---------------------------------------------------------------------------
__global__ __launch_bounds__(256)
void ln2_kernel(const unsigned short* __restrict__ xo,
                const float* __restrict__ w, const float* __restrict__ b,
                unsigned short* __restrict__ out) {
  const int t = blockIdx.x * 4 + (threadIdx.x >> 6);
  const int lane = threadIdx.x & 63;
  const unsigned short* src = xo + (size_t)t * 384;
  float v[6];
  float s = 0.f, s2 = 0.f;
#pragma unroll
  for (int j = 0; j < 3; ++j) {
    const uint32_t u = *(const uint32_t*)&src[j * 128 + lane * 2];
    const float a = bf2f(u), c = bf2f(u >> 16);
    v[2 * j] = a;
    v[2 * j + 1] = c;
    s += a + c;
    s2 += a * a + c * c;
  }
#pragma unroll
  for (int m = 1; m < 64; m <<= 1) {
    s += __shfl_xor(s, m, 64);
    s2 += __shfl_xor(s2, m, 64);
  }
  const float mu = s * (1.f / 384.f);
  const float rs = rsqrtf(s2 * (1.f / 384.f) - mu * mu + 1e-5f);
#pragma unroll
  for (int j = 0; j < 3; ++j) {
    const int c0 = j * 128 + lane * 2;
    *(uint32_t*)&out[(size_t)t * 384 + c0] =
        pack2((v[2 * j] - mu) * rs * w[c0] + b[c0],
              (v[2 * j + 1] - mu) * rs * w[c0 + 1] + b[c0 + 1]);
  }
}

// ---------------------------------------------------------------------------
// bf16 GEMM: C[M,N] = A[M,K] @ B[N,K]^T (+bias), 128x128 tile, BK=64,
// 4 waves (2x2), 16x16x32 MFMA.  SINGLE-buffered LDS (32 KB -> ~5 blocks/CU;
// m97 structure): per K-step {STAGE; syncthreads; COMPUTE; syncthreads}.
// Cross-block phase stagger provides the pipe overlap (m114) that explicit
// dbuf at 2 blocks/CU could not.  XOR-swizzled LDS (0 conflicts).  XCD
// block swizzle.
// EPI: 0=QKV scatter (q scaled), 1=proj+reverse+residual(fp32 x)->xo bf16,
//      2=GELU->h1 bf16, 3=+xo(bf16) residual->d_out fp32.
// ---------------------------------------------------------------------------
template <int EPI>
__global__ __launch_bounds__(256, 4)
void gemm_bt(const unsigned short* __restrict__ A,
             const unsigned short* __restrict__ Bw,
             const float* __restrict__ bias, const void* __restrict__ res,
             void* __restrict__ out0, int M, int N, int K) {
  __shared__ unsigned short As[128 * 64];
  __shared__ unsigned short Bs[128 * 64];
  const int tid = threadIdx.x;
  const int wave = tid >> 6, lane = tid & 63;
  const int lr = lane & 15, kg = lane >> 4;
  const int wm = wave >> 1, wn = wave & 1;

  // XCD-chunked bijective block swizzle (nwg % 8 == 0 for all our grids)
  const int gx = gridDim.x;
  const int nwg = gx * gridDim.y;
  int bid = blockIdx.y * gx + blockIdx.x;
  bid = (bid & 7) * (nwg >> 3) + (bid >> 3);
  const int tile_n = (bid % gx) * 128;
  const int tile_m = (bid / gx) * 128;

  // staging: lane covers row (lane>>3) of the 8-row stripe, 16B granule
  // (lane&7); source granule pre-swizzled so that a swizzled READ is correct.
  const int srow = lane >> 3;
  const int scol = ((lane & 7) ^ srow) * 8;   // bf16 elems

  const f32x4 z4 = {0.f, 0.f, 0.f, 0.f};
  f32x4 acc[4][4];
#pragma unroll
  for (int i = 0; i < 4; ++i)
#pragma unroll
    for (int j = 0; j < 4; ++j) acc[i][j] = z4;

  const unsigned short* Ab = A + (size_t)tile_m * K;
  const unsigned short* Bb = Bw + (size_t)tile_n * K;

  auto STAGE = [&](int kt) {   // 8 global_load_lds per thread
#pragma unroll
    for (int i = 0; i < 4; ++i) {
      const int r0 = wave * 32 + i * 8;
      async_cp16(&Ab[(size_t)(r0 + srow) * K + kt + scol], &As[r0 * 64]);
      async_cp16(&Bb[(size_t)(r0 + srow) * K + kt + scol], &Bs[r0 * 64]);
    }
  };

  auto COMPUTE = [&]() {
#pragma unroll
    for (int kk = 0; kk < 2; ++kk) {
      const int gsw = ((kk * 4 + kg) ^ (lr & 7)) * 8;  // swizzled granule
      bf16x8 af[4], bfr[4];
#pragma unroll
      for (int mf = 0; mf < 4; ++mf)
        af[mf] = *(const bf16x8*)&As[(wm * 64 + mf * 16 + lr) * 64 + gsw];
#pragma unroll
      for (int nf = 0; nf < 4; ++nf)
        bfr[nf] = *(const bf16x8*)&Bs[(wn * 64 + nf * 16 + lr) * 64 + gsw];
#pragma unroll
      for (int mf = 0; mf < 4; ++mf)
#pragma unroll
        for (int nf = 0; nf < 4; ++nf)
          acc[mf][nf] = mfma16(af[mf], bfr[nf], acc[mf][nf]);
    }
  };

  for (int kt = 0; kt < K; kt += 64) {
    STAGE(kt);
    __syncthreads();     // drains vmcnt(0): tile ready for all waves
    COMPUTE();
    __syncthreads();     // all waves done reading before next STAGE
  }

#pragma unroll
  for (int mf = 0; mf < 4; ++mf) {
#pragma unroll
    for (int nf = 0; nf < 4; ++nf) {
#pragma unroll
      for (int r = 0; r < 4; ++r) {
        const int row = tile_m + wm * 64 + mf * 16 + kg * 4 + r;
        const int col = tile_n + wn * 64 + nf * 16 + lr;
        float v = acc[mf][nf][r] + bias[col];
        if constexpr (EPI == 0) {
          const int s = col / 384;
          const int cc = col - s * 384;
          const int hh = cc >> 5, d = cc & 31;
          if (s == 0) v *= 0.17677669529663689f;  // HD^-0.5
          const int b_ = row >> 6, tok = row & 63;
          ((unsigned short*)out0)[(size_t)s * QSZ +
                                  ((size_t)(b_ * 12 + hh) * 64 + tok) * 32 + d] =
              f2bf(v);
        } else if constexpr (EPI == 1) {
          const int b_ = row >> 6, tok = row & 63;
          const int wI = b_ % 144, bb = b_ / 144;
          const int ph = ((wI / 12) * 8 + (tok >> 3) + 4) % 96;
          const int pw = ((wI % 12) * 8 + (tok & 7) + 4) % 96;
          const size_t pix = (size_t)(bb * 96 + ph) * 96 + pw;
          // res = original x (fp32, raw-reshape layout); out = xo bf16
          ((unsigned short*)out0)[pix * 384 + col] =
              f2bf(((const float*)res)[pix * 384 + col] + v);
        } else if constexpr (EPI == 2) {
          // cheap GELU: v * sigmoid(1.702 v)
          const float g = v / (1.f + __expf(-1.702f * v));
          ((unsigned short*)out0)[(size_t)row * 1536 + col] = f2bf(g);
        } else {
          // res = xo bf16; out = d_out fp32
          const float rv =
              bf2f(((const unsigned short*)res)[(size_t)row * 384 + col]);
          ((float*)out0)[(size_t)row * 384 + col] = rv + v;
        }
      }
    }
  }
}

// ---------------------------------------------------------------------------
// Windowed attention: one block (4 waves) per (b_, head).
// q,k,v: (B_, NH, 64, 32) bf16.  out_t: (B_*64, 384) bf16 token-major.
// P and vT LDS tiles XOR-swizzled (scalar writes swizzled, b128 reads too).
// ---------------------------------------------------------------------------
__global__ __launch_bounds__(256)
void attn_kernel(const unsigned short* __restrict__ qkv,
                 const float* __restrict__ rpb,
                 unsigned short* __restrict__ out_t) {
  const int bh = blockIdx.x;
  const int b_ = bh / 12, h = bh % 12;
  const int tid = threadIdx.x, wave = tid >> 6, lane = tid & 63;
  const int lr = lane & 15, kg = lane >> 4;
  const unsigned short* qb = qkv + (size_t)(b_ * 12 + h) * 64 * 32;
  const unsigned short* kb = qb + QSZ;
  const unsigned short* vb = qb + 2u * QSZ;

  __shared__ unsigned short P[64 * 64];
  __shared__ unsigned short vT[32 * 64];

  // stage v^T into LDS: vT[d][tok], col swizzled by (d&7)<<3
  {
    const int tok = tid >> 2, d0 = (tid & 3) * 8;
    const unsigned short* vp = &vb[tok * 32 + d0];
#pragma unroll
    for (int j = 0; j < 8; ++j)
      vT[(d0 + j) * 64 + (tok ^ (j << 3))] = vp[j];
  }

  // QK^T: rows wave*16..+15, all 64 cols
  const bf16x8 aq = *(const bf16x8*)&qb[(wave * 16 + lr) * 32 + kg * 8];
  f32x4 sc[4];
  const f32x4 z4 = {0.f, 0.f, 0.f, 0.f};
#pragma unroll
  for (int cb = 0; cb < 4; ++cb) {
    const bf16x8 bk = *(const bf16x8*)&kb[(cb * 16 + lr) * 32 + kg * 8];
    sc[cb] = mfma16(aq, bk, z4);
  }

  // bias + mask + softmax (row fully inside one 16-lane group)
  const int wI = b_ % 144;
  const int whi = wI / 12, wwi = wI % 12;
#pragma unroll
  for (int r = 0; r < 4; ++r) {
    const int row = wave * 16 + kg * 4 + r;
    const int rh = (whi < 11) ? 0 : (((row >> 3) < 4) ? 1 : 2);
    const int rw = (wwi < 11) ? 0 : (((row & 7) < 4) ? 1 : 2);
    float sv[4];
    float mx = -1e30f;
#pragma unroll
    for (int cb = 0; cb < 4; ++cb) {
      const int col = cb * 16 + lr;
      const int dr = (row >> 3) - (col >> 3) + 7;
      const int dc = (row & 7) - (col & 7) + 7;
      const float bias = rpb[(dr * 15 + dc) * 12 + h];
      const int ch = (whi < 11) ? 0 : (((col >> 3) < 4) ? 1 : 2);
      const int cw = (wwi < 11) ? 0 : (((col & 7) < 4) ? 1 : 2);
      float val = sc[cb][r] + bias + ((rh == ch && rw == cw) ? 0.f : -100.f);
      sv[cb] = val;
      mx = fmaxf(mx, val);
    }
#pragma unroll
    for (int o = 1; o < 16; o <<= 1) mx = fmaxf(mx, __shfl_xor(mx, o, 64));
    float sum = 0.f;
#pragma unroll
    for (int cb = 0; cb < 4; ++cb) {
      sv[cb] = __expf(sv[cb] - mx);
      sum += sv[cb];
    }
#pragma unroll
    for (int o = 1; o < 16; o <<= 1) sum += __shfl_xor(sum, o, 64);
    const float inv = 1.f / sum;
    const int psw = (row & 7) << 3;
#pragma unroll
    for (int cb = 0; cb < 4; ++cb)
      P[row * 64 + ((cb * 16 + lr) ^ psw)] = f2bf(sv[cb] * inv);
  }
  __syncthreads();

  // PV: out rows wave*16..+15, cols 0..31; K=64 in two 32-slices
  f32x4 o0 = z4, o1 = z4;
  const int rsw = (lr & 7) << 3;
#pragma unroll
  for (int ks = 0; ks < 2; ++ks) {
    const int e = (ks * 32 + kg * 8);
    const bf16x8 ap =
        *(const bf16x8*)&P[(wave * 16 + lr) * 64 + (e ^ rsw)];
    const bf16x8 b0 = *(const bf16x8*)&vT[(0 + lr) * 64 + (e ^ rsw)];
    const bf16x8 b1 = *(const bf16x8*)&vT[(16 + lr) * 64 + (e ^ rsw)];
    o0 = mfma16(ap, b0, o0);
    o1 = mfma16(ap, b1, o1);
  }
  unsigned short* ob = out_t + (size_t)(b_ * 64) * 384 + h * 32;
#pragma unroll
  for (int r = 0; r < 4; ++r) {
    const int tok = wave * 16 + kg * 4 + r;
    ob[(size_t)tok * 384 + lr] = f2bf(o0[r]);
    ob[(size_t)tok * 384 + 16 + lr] = f2bf(o1[r]);
  }
}

// ---------------------------------------------------------------------------
extern "C" void kernel_launch(void* const* d_in, const int* in_sizes, int n_in,
                              void* d_out, int out_size, void* d_ws,
                              size_t ws_size, hipStream_t stream) {
  const float* x      = (const float*)d_in[0];
  const float* qkv_w  = (const float*)d_in[1];
  const float* qkv_b  = (const float*)d_in[2];
  const float* rpb    = (const float*)d_in[3];
  const float* proj_w = (const float*)d_in[4];
  const float* proj_b = (const float*)d_in[5];
  const float* n1w    = (const float*)d_in[6];
  const float* n1b    = (const float*)d_in[7];
  const float* n2w    = (const float*)d_in[8];
  const float* n2b    = (const float*)d_in[9];
  const float* fc1_w  = (const float*)d_in[10];
  const float* fc1_b  = (const float*)d_in[11];
  const float* fc2_w  = (const float*)d_in[12];
  const float* fc2_b  = (const float*)d_in[13];

  char* ws = (char*)d_ws;
  const size_t SZ_A = 56623104;    // 73728*384*2  (bf16 act)
  const size_t SZ_Q = 3 * SZ_A;    // q,k,v bf16

  unsigned short* Xw    = (unsigned short*)(ws);
  unsigned short* qkv   = (unsigned short*)(ws + SZ_A);
  unsigned short* xo    = (unsigned short*)(ws + SZ_A + SZ_Q);        // bf16
  unsigned short* xon   = (unsigned short*)(ws + SZ_A + SZ_Q + SZ_A); // bf16
  unsigned short* wbuf  = (unsigned short*)(ws + SZ_A + SZ_Q + 2 * SZ_A);
  unsigned short* wqkv  = wbuf;
  unsigned short* wproj = wqkv + 1152 * 384;
  unsigned short* wfc1  = wproj + 384 * 384;
  unsigned short* wfc2  = wfc1 + 1536 * 384;
  unsigned short* attn_o = Xw;               // reuse after QKV consumed Xw
  unsigned short* h1     = (unsigned short*)ws;  // 226.5MB, reuses Xw+qkv

  cvt_all_kernel<<<6912, 256, 0, stream>>>(qkv_w, proj_w, fc1_w, fc2_w, wbuf);

  ln1_kernel<<<MTOK / 4, 256, 0, stream>>>(x, n1w, n1b, Xw);

  gemm_bt<0><<<dim3(9, 576), 256, 0, stream>>>(Xw, wqkv, qkv_b, nullptr,
                                               qkv, MTOK, 1152, 384);

  attn_kernel<<<13824, 256, 0, stream>>>(qkv, rpb, attn_o);

  gemm_bt<1><<<dim3(3, 576), 256, 0, stream>>>(attn_o, wproj, proj_b, x,
                                               xo, MTOK, 384, 384);

  ln2_kernel<<<MTOK / 4, 256, 0, stream>>>(xo, n2w, n2b, xon);

  gemm_bt<2><<<dim3(12, 576), 256, 0, stream>>>(xon, wfc1, fc1_b, nullptr,
                                                h1, MTOK, 1536, 384);

  gemm_bt<3><<<dim3(3, 576), 256, 0, stream>>>(h1, wfc2, fc2_b, xo,
                                               (float*)d_out, MTOK, 384, 1536);
}